// Round 4
// baseline (2511.368 us; speedup 1.0000x reference)
//
#include <hip/hip_runtime.h>
#include <cstdint>

// Problem constants
#define CC   192          // channels
#define NTOK 32768        // B * H * W  (= 512 windows * 64)
#define HHH  128
#define WWW  128

__device__ __forceinline__ float gelu_f(float x) {
  // exact gelu: x * 0.5 * (1 + erf(x/sqrt(2)))
  return 0.5f * x * (1.0f + erff(x * 0.70710678118654752440f));
}

// ---------------------------------------------------------------------------
// K1: LayerNorm1 + window partition.  x (B,L,C) -> xw (512 windows, 64, 192)
// one wave per token, lane handles 3 channels
// ---------------------------------------------------------------------------
__global__ __launch_bounds__(256) void k_ln1(const float* __restrict__ x,
    const float* __restrict__ w, const float* __restrict__ b,
    float* __restrict__ xw) {
  int tok  = blockIdx.x * 4 + (threadIdx.x >> 6);
  int lane = threadIdx.x & 63;
  const float* xp = x + (size_t)tok * CC + lane * 3;
  float v0 = xp[0], v1 = xp[1], v2 = xp[2];
  float s = v0 + v1 + v2;
  #pragma unroll
  for (int off = 32; off >= 1; off >>= 1) s += __shfl_xor(s, off);
  float mean = s * (1.0f / 192.0f);
  float d0 = v0 - mean, d1 = v1 - mean, d2 = v2 - mean;
  float q = d0 * d0 + d1 * d1 + d2 * d2;
  #pragma unroll
  for (int off = 32; off >= 1; off >>= 1) q += __shfl_xor(q, off);
  float rstd = rsqrtf(q * (1.0f / 192.0f) + 1e-5f);
  int bb = tok >> 14, l = tok & 16383;
  int hy = l >> 7, wx = l & 127;
  int win = bb * 256 + (hy >> 3) * 16 + (wx >> 3);
  int n   = (hy & 7) * 8 + (wx & 7);
  int c = lane * 3;
  float* op = xw + ((size_t)win * 64 + n) * CC + c;
  op[0] = d0 * rstd * w[c]     + b[c];
  op[1] = d1 * rstd * w[c + 1] + b[c + 1];
  op[2] = d2 * rstd * w[c + 2] + b[c + 2];
}

// ---------------------------------------------------------------------------
// Generic fp32 tiled GEMM:  C[M,N] = act( A[M,K] * B[K,N] + bias ) [+ res]
//  - A row-major (lda); B row-major K x N (ldb) or, if btrans, stored N x K
//  - biasmode: 0 none, 1 per-row(M), 2 per-col(N);  act: 0 none, 1 gelu
//  - res != nullptr: elementwise add res[cm*ldc + n] (residual fusion)
//  - M,N multiples of 64, K multiple of 16 (all shapes here satisfy this)
// ---------------------------------------------------------------------------
__global__ __launch_bounds__(256) void k_gemm(const float* __restrict__ A,
    const float* __restrict__ B, float* __restrict__ Cmat,
    const float* __restrict__ bias, const float* __restrict__ res,
    int M, int N, int K, int lda, int ldb, int ldc,
    int btrans, int biasmode, int act) {
  __shared__ float As[16][68];
  __shared__ float Bs[16][68];
  int m0 = blockIdx.y * 64, n0 = blockIdx.x * 64;
  int tid = threadIdx.x;
  int tx = tid & 15, ty = tid >> 4;
  float acc[4][4] = {};
  for (int k0 = 0; k0 < K; k0 += 16) {
    #pragma unroll
    for (int i = tid; i < 1024; i += 256) {
      int kk = i & 15, mm = i >> 4;
      As[kk][mm] = A[(size_t)(m0 + mm) * lda + k0 + kk];
    }
    if (btrans) {
      #pragma unroll
      for (int i = tid; i < 1024; i += 256) {
        int kk = i & 15, nn = i >> 4;
        Bs[kk][nn] = B[(size_t)(n0 + nn) * ldb + k0 + kk];
      }
    } else {
      #pragma unroll
      for (int i = tid; i < 1024; i += 256) {
        int nn = i & 63, kk = i >> 6;
        Bs[kk][nn] = B[(size_t)(k0 + kk) * ldb + n0 + nn];
      }
    }
    __syncthreads();
    #pragma unroll
    for (int k = 0; k < 16; ++k) {
      float av[4], bv[4];
      #pragma unroll
      for (int u = 0; u < 4; ++u) { av[u] = As[k][ty * 4 + u]; bv[u] = Bs[k][tx * 4 + u]; }
      #pragma unroll
      for (int i2 = 0; i2 < 4; ++i2)
        #pragma unroll
        for (int j = 0; j < 4; ++j) acc[i2][j] += av[i2] * bv[j];
    }
    __syncthreads();
  }
  #pragma unroll
  for (int i2 = 0; i2 < 4; ++i2) {
    int cm = m0 + ty * 4 + i2;
    float bm = (biasmode == 1) ? bias[cm] : 0.0f;
    float4 r4 = make_float4(0.f, 0.f, 0.f, 0.f);
    if (res) r4 = *reinterpret_cast<const float4*>(&res[(size_t)cm * ldc + n0 + tx * 4]);
    float vals[4];
    #pragma unroll
    for (int j = 0; j < 4; ++j) {
      float vv = acc[i2][j] + bm;
      if (biasmode == 2) vv += bias[n0 + tx * 4 + j];
      if (act == 1) vv = gelu_f(vv);
      vals[j] = vv;
    }
    float4 o;
    o.x = vals[0] + r4.x; o.y = vals[1] + r4.y;
    o.z = vals[2] + r4.z; o.w = vals[3] + r4.w;
    *reinterpret_cast<float4*>(&Cmat[(size_t)cm * ldc + n0 + tx * 4]) = o;
  }
}

// ---------------------------------------------------------------------------
// 8x8 real-FFT basis:  T[p*64+q] = cos(pi/4 * ((p_hi*q_hi + p_lo*q_lo) & 7))
// symmetric; serves both Re(FFT) and Re(IFFT)
// ---------------------------------------------------------------------------
__device__ __forceinline__ void buildT(float* T, int tid) {
  const float R2 = 0.70710678118654752440f;
  for (int i = tid; i < 4096; i += 256) {
    int p = i >> 6, qq = i & 63;
    int m = ((p >> 3) * (qq >> 3) + (p & 7) * (qq & 7)) & 7;
    float c;
    if (m == 0) c = 1.0f;
    else if (m == 4) c = -1.0f;
    else if (m == 2 || m == 6) c = 0.0f;
    else if (m == 1 || m == 7) c = R2;
    else c = -R2;
    T[i] = c;
  }
}

// xw (win,64,192) -> xfftT (192, 32768) : Re(FFT2) per channel per window
// channels processed in 2 halves of 96 to stay under 64 KB LDS
__global__ __launch_bounds__(256) void k_fft(const float* __restrict__ xw,
                                             float* __restrict__ xfftT) {
  __shared__ float T[4096];
  __shared__ float sw[64][96];  // [q][ch-half]
  int b_ = blockIdx.x, tid = threadIdx.x;
  buildT(T, tid);
  for (int half = 0; half < 2; ++half) {
    __syncthreads();
    for (int i = tid; i < 6144; i += 256) {
      int q = i / 96, ch = i % 96;
      sw[q][ch] = xw[(size_t)b_ * 12288 + q * 192 + half * 96 + ch];
    }
    __syncthreads();
    for (int idx = tid; idx < 6144; idx += 256) {
      int ch = idx >> 6, p = idx & 63;   // ch wave-uniform, p = lane
      float s = 0.0f;
      #pragma unroll
      for (int qq = 0; qq < 64; ++qq) s += T[qq * 64 + p] * sw[qq][ch];
      xfftT[(size_t)(half * 96 + ch) * NTOK + b_ * 64 + p] = s;
    }
  }
}

// y2 (192,32768) -> xifft (win, 192*64 flat) : (1/64) * Re(IFFT2)
__global__ __launch_bounds__(256) void k_ifft(const float* __restrict__ y2,
                                              float* __restrict__ xifft) {
  __shared__ float T[4096];
  __shared__ float sy[96][64];  // [ch-half][q]
  int b_ = blockIdx.x, tid = threadIdx.x;
  buildT(T, tid);
  for (int half = 0; half < 2; ++half) {
    __syncthreads();
    for (int i = tid; i < 6144; i += 256) {
      int ch = i >> 6, p = i & 63;
      sy[ch][p] = y2[(size_t)(half * 96 + ch) * NTOK + b_ * 64 + p];
    }
    __syncthreads();
    for (int idx = tid; idx < 6144; idx += 256) {
      int ch = idx >> 6, p = idx & 63;
      float s = 0.0f;
      #pragma unroll
      for (int qq = 0; qq < 64; ++qq) s += T[qq * 64 + p] * sy[ch][qq];
      xifft[(size_t)b_ * 12288 + (half * 96 + ch) * 64 + p] = s * 0.015625f;
    }
  }
}

// ---------------------------------------------------------------------------
// Attention kernel: one block per window.  Fuses the qkv depthwise 3x3 conv
// (over the (window, position) "image" incl. cross-window rows), the x_ifft
// add, per-head softmax with relative-position bias, and PV.
// Writes token-major aoTok (32768, 192).
// ---------------------------------------------------------------------------
__global__ __launch_bounds__(256) void k_attn(
    const float* __restrict__ t,       // (576, 32768) qkv-conv1x1 output (+bias)
    const float* __restrict__ xifft,   // (512, 12288)
    const float* __restrict__ dww,     // (576, 9)
    const float* __restrict__ dwb,     // (576)
    const float* __restrict__ rpb,     // (225, 6)
    float* __restrict__ aoTok)         // (32768, 192)
{
  int b_ = blockIdx.x;
  int tid = threadIdx.x;
  int lane = tid & 63;
  int wv = tid >> 6;
  __shared__ float sq[64][33], sk[64][33], sv[64][33];
  __shared__ float ssc[64][65];
  const float SCALE = 0.17677669529663687f;  // 32^-0.5

  for (int h = 0; h < 6; ++h) {
    // build q,k,v:  3 s * 64 n * 32 d
    for (int idx = tid; idx < 6144; idx += 256) {
      int n = idx & 63;
      int sd = idx >> 6;
      int s = sd >> 5;
      int d = sd & 31;
      int o = s * 192 + h * 32 + d;
      const float* w9 = dww + o * 9;
      float acc = dwb[o];
      const float* trow = t + (size_t)o * NTOK;
      #pragma unroll
      for (int dy = -1; dy <= 1; ++dy) {
        int bb = b_ + dy;
        if (bb < 0 || bb >= 512) continue;
        const float* tr = trow + bb * 64;
        #pragma unroll
        for (int dx = -1; dx <= 1; ++dx) {
          int nn = n + dx;
          if (nn < 0 || nn >= 64) continue;
          acc += w9[(dy + 1) * 3 + (dx + 1)] * tr[nn];
        }
      }
      float xr = xifft[(size_t)b_ * 12288 + h * 2048 + n * 32 + d];
      if (s == 0)      sq[n][d] = (acc + xr) * SCALE;
      else if (s == 1) sk[n][d] = acc + xr;
      else             sv[n][d] = acc + xr;
    }
    __syncthreads();
    // scores + bias
    #pragma unroll
    for (int it = 0; it < 16; ++it) {
      int i = it * 4 + wv;
      int j = lane;
      float s = 0.0f;
      #pragma unroll
      for (int d = 0; d < 32; ++d) s += sq[i][d] * sk[j][d];
      int dyr = (i >> 3) - (j >> 3) + 7;
      int dxr = (i & 7) - (j & 7) + 7;
      s += rpb[(dyr * 15 + dxr) * 6 + h];
      ssc[i][j] = s;
    }
    __syncthreads();
    // softmax: 4 threads per row
    {
      int i = tid >> 2;
      int r = tid & 3;
      float mx = -1e30f;
      #pragma unroll
      for (int jj = 0; jj < 16; ++jj) mx = fmaxf(mx, ssc[i][r * 16 + jj]);
      mx = fmaxf(mx, __shfl_xor(mx, 1));
      mx = fmaxf(mx, __shfl_xor(mx, 2));
      float sum = 0.0f;
      float ev[16];
      #pragma unroll
      for (int jj = 0; jj < 16; ++jj) {
        ev[jj] = expf(ssc[i][r * 16 + jj] - mx);
        sum += ev[jj];
      }
      sum += __shfl_xor(sum, 1);
      sum += __shfl_xor(sum, 2);
      float inv = 1.0f / sum;
      #pragma unroll
      for (int jj = 0; jj < 16; ++jj) ssc[i][r * 16 + jj] = ev[jj] * inv;
    }
    __syncthreads();
    // PV + direct coalesced global write
    #pragma unroll
    for (int it = 0; it < 8; ++it) {
      int idx = tid + it * 256;
      int d = idx & 31;
      int i = idx >> 5;
      float s = 0.0f;
      #pragma unroll
      for (int j = 0; j < 64; ++j) s += ssc[i][j] * sv[j][d];
      aoTok[((size_t)b_ * 64 + i) * CC + h * 32 + d] = s;
    }
    __syncthreads();
  }
}

// ---------------------------------------------------------------------------
// Residual + LN2 stats:  xres = x + proj_out(window-token order); stats(mean,rstd)
// ---------------------------------------------------------------------------
__global__ __launch_bounds__(256) void k_resid(const float* __restrict__ x,
    const float* __restrict__ pout, float* __restrict__ xres,
    float* __restrict__ stats) {
  int tok = blockIdx.x * 4 + (threadIdx.x >> 6);
  int lane = threadIdx.x & 63;
  int bb = tok >> 14, l = tok & 16383;
  int hy = l >> 7, wx = l & 127;
  int col = (bb * 256 + (hy >> 3) * 16 + (wx >> 3)) * 64 + (hy & 7) * 8 + (wx & 7);
  int c = lane * 3;
  const float* xp = x + (size_t)tok * CC + c;
  const float* pp = pout + (size_t)col * CC + c;
  float v0 = xp[0] + pp[0], v1 = xp[1] + pp[1], v2 = xp[2] + pp[2];
  float* rp = xres + (size_t)tok * CC + c;
  rp[0] = v0; rp[1] = v1; rp[2] = v2;
  float s = v0 + v1 + v2;
  #pragma unroll
  for (int off = 32; off >= 1; off >>= 1) s += __shfl_xor(s, off);
  float mean = s * (1.0f / 192.0f);
  float d0 = v0 - mean, d1 = v1 - mean, d2 = v2 - mean;
  float q = d0 * d0 + d1 * d1 + d2 * d2;
  #pragma unroll
  for (int off = 32; off >= 1; off >>= 1) q += __shfl_xor(q, off);
  float rstd = rsqrtf(q * (1.0f / 192.0f) + 1e-5f);
  if (lane == 0) { stats[tok * 2] = mean; stats[tok * 2 + 1] = rstd; }
}

// LN2 apply + transpose to channel-major yT (192, 32768)
__global__ __launch_bounds__(256) void k_lnT(const float* __restrict__ xres,
    const float* __restrict__ stats, const float* __restrict__ w,
    const float* __restrict__ b, float* __restrict__ yT) {
  __shared__ float tile[32][33];
  int t0 = blockIdx.x * 32;
  int c0 = blockIdx.y * 32;
  int tid = threadIdx.x;
  #pragma unroll
  for (int i = tid; i < 1024; i += 256) {
    int row = i >> 5, col = i & 31;        // row: token, col: channel
    int tok = t0 + row, c = c0 + col;
    float v = xres[(size_t)tok * CC + c];
    tile[row][col] = (v - stats[tok * 2]) * stats[tok * 2 + 1] * w[c] + b[c];
  }
  __syncthreads();
  #pragma unroll
  for (int i = tid; i < 1024; i += 256) {
    int row = i >> 5, col = i & 31;        // row: channel, col: token
    yT[(size_t)(c0 + row) * NTOK + t0 + col] = tile[col][row];
  }
}

// ---------------------------------------------------------------------------
// Fused FFN middle (chunked): operates on a 64-row horizontal strip.
// ff0 holds rows [row0, row0+68) of one batch image, layout (1536, 68*128).
// Output tile rows are [r0, r0+64); x1cat layout (1536, 64*128).
// ---------------------------------------------------------------------------
__global__ __launch_bounds__(256) void k_ffmid(const float* __restrict__ ff0,
    const float* __restrict__ dw3w, const float* __restrict__ dw5w,
    const float* __restrict__ dw31w, const float* __restrict__ dw51w,
    float* __restrict__ x1cat, int r0, int row0) {
  int m = blockIdx.y;
  int ty0 = r0 + (blockIdx.x >> 3) * 16, tx0 = (blockIdx.x & 7) * 16;
  __shared__ float sA[2][24][24];
  __shared__ float aloc[2][20][20];
  __shared__ float bloc[2][20][20];
  int tid = threadIdx.x;
  for (int i = tid; i < 576; i += 256) {
    int yy = i / 24, xx = i % 24;
    int gy = ty0 - 4 + yy, gx = tx0 - 4 + xx;
    bool ok = (gy >= 0 && gy < HHH && gx >= 0 && gx < WWW);
    size_t base = (size_t)(2 * m) * 8704 + (size_t)(ok ? ((gy - row0) * WWW + gx) : 0);
    sA[0][yy][xx] = ok ? ff0[base] : 0.0f;
    sA[1][yy][xx] = ok ? ff0[base + 8704] : 0.0f;
  }
  __syncthreads();
  for (int i = tid; i < 400; i += 256) {
    int yy = i / 20, xx = i % 20;
    int gy = ty0 - 2 + yy, gx = tx0 - 2 + xx;
    bool in = (gy >= 0 && gy < HHH && gx >= 0 && gx < WWW);
    #pragma unroll
    for (int kk = 0; kk < 2; ++kk) {
      int ch = 2 * m + kk;
      const float* w3 = dw3w + ch * 9;
      const float* w5 = dw5w + ch * 25;
      float s3 = 0.0f, s5 = 0.0f;
      #pragma unroll
      for (int dy = 0; dy < 5; ++dy)
        #pragma unroll
        for (int dx = 0; dx < 5; ++dx) {
          float vv = sA[kk][yy + dy][xx + dx];
          s5 += w5[dy * 5 + dx] * vv;
          if (dy >= 1 && dy <= 3 && dx >= 1 && dx <= 3)
            s3 += w3[(dy - 1) * 3 + (dx - 1)] * vv;
        }
      aloc[kk][yy][xx] = in ? fmaxf(s3, 0.0f) : 0.0f;
      bloc[kk][yy][xx] = in ? fmaxf(s5, 0.0f) : 0.0f;
    }
  }
  __syncthreads();
  int oy = tid >> 4, ox = tid & 15;
  bool small = (m < 384);
  const float* kA = small ? (dw31w + m * 18)         : (dw51w + (m - 384) * 50);
  const float* kB = small ? (dw31w + (m + 384) * 18) : (dw51w + m * 50);
  int ochA = small ? m       : m + 384;
  int ochB = small ? m + 384 : 768 + m;
  int ksz = small ? 3 : 5;
  int r   = small ? 1 : 2;
  float sAo = 0.0f, sBo = 0.0f;
  for (int kk2 = 0; kk2 < 2; ++kk2) {
    for (int dy = -r; dy <= r; ++dy)
      for (int dx = -r; dx <= r; ++dx) {
        int widx = kk2 * ksz * ksz + (dy + r) * ksz + (dx + r);
        sAo += kA[widx] * aloc[kk2][oy + 2 + dy][ox + 2 + dx];
        sBo += kB[widx] * bloc[kk2][oy + 2 + dy][ox + 2 + dx];
      }
  }
  size_t px = (size_t)(ty0 - r0 + oy) * WWW + tx0 + ox;
  x1cat[(size_t)ochA * 8192 + px] = gelu_f(sAo);
  x1cat[(size_t)ochB * 8192 + px] = gelu_f(sBo);
}

// ---------------------------------------------------------------------------
extern "C" void kernel_launch(void* const* d_in, const int* in_sizes, int n_in,
                              void* d_out, int out_size, void* d_ws, size_t ws_size,
                              hipStream_t stream) {
  (void)in_sizes; (void)n_in;
  const float* x      = (const float*)d_in[0];
  const float* ln1w   = (const float*)d_in[1];
  const float* ln1b   = (const float*)d_in[2];
  const float* rpb    = (const float*)d_in[3];
  const float* qkvw   = (const float*)d_in[4];
  const float* qkvb   = (const float*)d_in[5];
  const float* qkvdww = (const float*)d_in[6];
  const float* qkvdwb = (const float*)d_in[7];
  const float* q1w    = (const float*)d_in[8];
  const float* q2w    = (const float*)d_in[9];
  const float* projw  = (const float*)d_in[10];
  const float* projb  = (const float*)d_in[11];
  const float* ln2w   = (const float*)d_in[12];
  const float* ln2b   = (const float*)d_in[13];
  const float* pinw   = (const float*)d_in[14];
  const float* dw3w   = (const float*)d_in[15];
  const float* dw5w   = (const float*)d_in[16];
  const float* dw31w  = (const float*)d_in[17];
  const float* dw51w  = (const float*)d_in[18];
  const float* poutw  = (const float*)d_in[19];
  float* out = (float*)d_out;
  float* ws  = (float*)d_ws;

  const size_t SZ = 6291456;            // 32768 * 192 floats (24 MiB)
  const size_t NEED = 7 * SZ * 4;       // 168 MiB total
  if (ws_size < NEED) {
    // Workspace too small: emit a clean miscompare (x -> out) instead of OOB.
    hipMemcpyAsync(d_out, d_in[0], (size_t)out_size * sizeof(float),
                   hipMemcpyDeviceToDevice, stream);
    return;
  }

  // Slot overlay (lifetimes verified against stream order):
  float* xres  = ws;                    // slot0: persists to end
  float* xw    = ws + SZ;               // slot1: xw -> y1 -> aoTok -> yT
  float* xfftT = ws + 2 * SZ;           // slot2: fft out -> y2 -> projo
  float* xifft = ws + 3 * SZ;           // slot3
  float* t     = ws + 4 * SZ;           // slots 4-6 (576 x 32768)
  float* stats = ws + 4 * SZ;           // reuses t region (t dead at resid time)
  float* y1    = xw;                    // after fft consumed xw
  float* aoTok = xw;                    // after q2 consumed y1
  float* yT    = xw;                    // after proj consumed aoTok
  float* projo = xfftT;                 // after ifft consumed y2
  float* ff0   = ws + 2 * SZ;           // phase2: 1536 x 8704 (13.37M floats)
  float* x1cat = ws + 26214400;         // phase2: 1536 x 8192 (12.58M floats)

  // --- attention phase ---
  k_ln1<<<8192, 256, 0, stream>>>(x, ln1w, ln1b, xw);
  // qkv 1x1: t(576,32768) = qkv_w @ xw^T + qkv_b
  k_gemm<<<dim3(512, 9), 256, 0, stream>>>(qkvw, xw, t, qkvb, nullptr,
      576, 32768, 192, 192, 192, 32768, 1, 1, 0);
  k_fft<<<512, 256, 0, stream>>>(xw, xfftT);
  // q1 (gelu) then q2
  k_gemm<<<dim3(512, 3), 256, 0, stream>>>(q1w, xfftT, y1, nullptr, nullptr,
      192, 32768, 192, 192, 32768, 32768, 0, 0, 1);
  k_gemm<<<dim3(512, 3), 256, 0, stream>>>(q2w, y1, xfftT, nullptr, nullptr,
      192, 32768, 192, 192, 32768, 32768, 0, 0, 0);
  k_ifft<<<512, 256, 0, stream>>>(xfftT, xifft);
  k_attn<<<512, 256, 0, stream>>>(t, xifft, qkvdww, qkvdwb, rpb, aoTok);
  // proj: (32768,192) @ proj_w^T + proj_b
  k_gemm<<<dim3(3, 512), 256, 0, stream>>>(aoTok, projw, projo, projb, nullptr,
      32768, 192, 192, 192, 192, 192, 1, 2, 0);
  k_resid<<<8192, 256, 0, stream>>>(x, projo, xres, stats);
  k_lnT<<<dim3(1024, 6), 256, 0, stream>>>(xres, stats, ln2w, ln2b, yT);

  // --- FFN phase: per (batch, half-image strip) to bound workspace ---
  for (int bb = 0; bb < 2; ++bb) {
    for (int ci = 0; ci < 2; ++ci) {
      int r0   = ci * 64;                       // output rows [r0, r0+64)
      int row0 = (ci == 0) ? 0 : 60;            // ff0 rows [row0, row0+68)
      // pin: ff0(1536, 8704) = pin_w @ yT_chunk
      k_gemm<<<dim3(136, 24), 256, 0, stream>>>(pinw,
          yT + bb * 16384 + row0 * WWW, ff0, nullptr, nullptr,
          1536, 8704, 192, 192, 32768, 8704, 0, 0, 0);
      k_ffmid<<<dim3(32, 768), 256, 0, stream>>>(ff0, dw3w, dw5w, dw31w, dw51w,
          x1cat, r0, row0);
      // pout + fused residual -> final out (flat identity reshape)
      k_gemm<<<dim3(128, 3), 256, 0, stream>>>(poutw, x1cat,
          out + (size_t)bb * 3145728 + r0 * WWW,
          nullptr, xres + (size_t)bb * 3145728 + r0 * WWW,
          192, 8192, 1536, 1536, 8192, 16384, 0, 0, 0);
    }
  }
}

// Round 10
// 2077.535 us; speedup vs baseline: 1.2088x; 1.2088x over previous
//
#include <hip/hip_runtime.h>
#include <cstdint>

// Problem constants
#define CC   192          // channels
#define NTOK 32768        // B * H * W  (= 512 windows * 64)
#define HHH  128
#define WWW  128

__device__ __forceinline__ float gelu_f(float x) {
  return 0.5f * x * (1.0f + erff(x * 0.70710678118654752440f));
}

// ---------------------------------------------------------------------------
// K1: LayerNorm1 + window partition.  x (B,L,C) -> xw (512 windows, 64, 192)
// ---------------------------------------------------------------------------
__global__ __launch_bounds__(256) void k_ln1(const float* __restrict__ x,
    const float* __restrict__ w, const float* __restrict__ b,
    float* __restrict__ xw) {
  int tok  = blockIdx.x * 4 + (threadIdx.x >> 6);
  int lane = threadIdx.x & 63;
  const float* xp = x + (size_t)tok * CC + lane * 3;
  float v0 = xp[0], v1 = xp[1], v2 = xp[2];
  float s = v0 + v1 + v2;
  #pragma unroll
  for (int off = 32; off >= 1; off >>= 1) s += __shfl_xor(s, off);
  float mean = s * (1.0f / 192.0f);
  float d0 = v0 - mean, d1 = v1 - mean, d2 = v2 - mean;
  float q = d0 * d0 + d1 * d1 + d2 * d2;
  #pragma unroll
  for (int off = 32; off >= 1; off >>= 1) q += __shfl_xor(q, off);
  float rstd = rsqrtf(q * (1.0f / 192.0f) + 1e-5f);
  int bb = tok >> 14, l = tok & 16383;
  int hy = l >> 7, wx = l & 127;
  int win = bb * 256 + (hy >> 3) * 16 + (wx >> 3);
  int n   = (hy & 7) * 8 + (wx & 7);
  int c = lane * 3;
  float* op = xw + ((size_t)win * 64 + n) * CC + c;
  op[0] = d0 * rstd * w[c]     + b[c];
  op[1] = d1 * rstd * w[c + 1] + b[c + 1];
  op[2] = d2 * rstd * w[c + 2] + b[c + 2];
}

// ---------------------------------------------------------------------------
// Templated fp32 tiled GEMM: C[M,N] = act(A[M,K]*B[K,N] + bias) [+ res]
// BM x BN block tile, TM x TN per thread, 256 threads, K-step 16.
// A row-major (lda). B row-major KxN (ldb) or, if btrans, stored NxK.
// biasmode: 0 none, 1 per-row(M), 2 per-col(N). act: 0 none, 1 gelu.
// ---------------------------------------------------------------------------
template<int BM, int BN, int TM, int TN>
__global__ __launch_bounds__(256) void k_gemmT(const float* __restrict__ A,
    const float* __restrict__ B, float* __restrict__ Cmat,
    const float* __restrict__ bias, const float* __restrict__ res,
    int K, int lda, int ldb, int ldc, int btrans, int biasmode, int act) {
  __shared__ alignas(16) float As[16][BM + 4];
  __shared__ alignas(16) float Bs[16][BN + 4];
  int m0 = blockIdx.y * BM, n0 = blockIdx.x * BN;
  int tid = threadIdx.x;
  constexpr int NTX = BN / TN;
  int tx = tid % NTX, ty = tid / NTX;
  float acc[TM][TN] = {};
  for (int k0 = 0; k0 < K; k0 += 16) {
    #pragma unroll
    for (int i = tid; i < BM * 4; i += 256) {
      int mm = i >> 2, kk = (i & 3) * 4;
      float4 v = *reinterpret_cast<const float4*>(&A[(size_t)(m0 + mm) * lda + k0 + kk]);
      As[kk][mm] = v.x; As[kk + 1][mm] = v.y; As[kk + 2][mm] = v.z; As[kk + 3][mm] = v.w;
    }
    if (btrans) {
      #pragma unroll
      for (int i = tid; i < BN * 4; i += 256) {
        int nn = i >> 2, kk = (i & 3) * 4;
        float4 v = *reinterpret_cast<const float4*>(&B[(size_t)(n0 + nn) * ldb + k0 + kk]);
        Bs[kk][nn] = v.x; Bs[kk + 1][nn] = v.y; Bs[kk + 2][nn] = v.z; Bs[kk + 3][nn] = v.w;
      }
    } else {
      #pragma unroll
      for (int i = tid; i < BN * 4; i += 256) {
        int kk = i / (BN / 4), nn4 = (i % (BN / 4)) * 4;
        *reinterpret_cast<float4*>(&Bs[kk][nn4]) =
            *reinterpret_cast<const float4*>(&B[(size_t)(k0 + kk) * ldb + n0 + nn4]);
      }
    }
    __syncthreads();
    #pragma unroll
    for (int k = 0; k < 16; ++k) {
      float av[TM], bv[TN];
      #pragma unroll
      for (int u = 0; u < TM; u += 4)
        *reinterpret_cast<float4*>(&av[u]) = *reinterpret_cast<const float4*>(&As[k][ty * TM + u]);
      #pragma unroll
      for (int u = 0; u < TN; u += 4)
        *reinterpret_cast<float4*>(&bv[u]) = *reinterpret_cast<const float4*>(&Bs[k][tx * TN + u]);
      #pragma unroll
      for (int im = 0; im < TM; ++im)
        #pragma unroll
        for (int jn = 0; jn < TN; ++jn)
          acc[im][jn] = fmaf(av[im], bv[jn], acc[im][jn]);
    }
    __syncthreads();
  }
  #pragma unroll
  for (int im = 0; im < TM; ++im) {
    int cm = m0 + ty * TM + im;
    float bm = (biasmode == 1) ? bias[cm] : 0.0f;
    #pragma unroll
    for (int jn = 0; jn < TN; jn += 4) {
      int cn = n0 + tx * TN + jn;
      float4 r4 = make_float4(0.f, 0.f, 0.f, 0.f);
      if (res) r4 = *reinterpret_cast<const float4*>(&res[(size_t)cm * ldc + cn]);
      float vv[4];
      #pragma unroll
      for (int u = 0; u < 4; ++u) {
        float t = acc[im][jn + u] + bm;
        if (biasmode == 2) t += bias[cn + u];
        if (act == 1) t = gelu_f(t);
        vv[u] = t;
      }
      float4 o;
      o.x = vv[0] + r4.x; o.y = vv[1] + r4.y; o.z = vv[2] + r4.z; o.w = vv[3] + r4.w;
      *reinterpret_cast<float4*>(&Cmat[(size_t)cm * ldc + cn]) = o;
    }
  }
}

// ---------------------------------------------------------------------------
// 8x8 real-FFT basis (symmetric; serves Re(FFT) and Re(IFFT))
// ---------------------------------------------------------------------------
__device__ __forceinline__ void buildT(float* T, int tid) {
  const float R2 = 0.70710678118654752440f;
  for (int i = tid; i < 4096; i += 256) {
    int p = i >> 6, qq = i & 63;
    int m = ((p >> 3) * (qq >> 3) + (p & 7) * (qq & 7)) & 7;
    float c;
    if (m == 0) c = 1.0f;
    else if (m == 4) c = -1.0f;
    else if (m == 2 || m == 6) c = 0.0f;
    else if (m == 1 || m == 7) c = R2;
    else c = -R2;
    T[i] = c;
  }
}

// xw (win,64,192) -> xfftT (192, 32768) : Re(FFT2)
__global__ __launch_bounds__(256) void k_fft(const float* __restrict__ xw,
                                             float* __restrict__ xfftT) {
  __shared__ float T[4096];
  __shared__ float sw[64][96];
  int b_ = blockIdx.x, tid = threadIdx.x;
  buildT(T, tid);
  for (int half = 0; half < 2; ++half) {
    __syncthreads();
    for (int i = tid; i < 6144; i += 256) {
      int q = i / 96, ch = i % 96;
      sw[q][ch] = xw[(size_t)b_ * 12288 + q * 192 + half * 96 + ch];
    }
    __syncthreads();
    for (int idx = tid; idx < 6144; idx += 256) {
      int ch = idx >> 6, p = idx & 63;
      float s = 0.0f;
      #pragma unroll
      for (int qq = 0; qq < 64; ++qq) s += T[qq * 64 + p] * sw[qq][ch];
      xfftT[(size_t)(half * 96 + ch) * NTOK + b_ * 64 + p] = s;
    }
  }
}

// ---------------------------------------------------------------------------
// y2 (192,32768) -> xifft2 (192, 32768) channel-major of the RESHAPED tensor:
// xifft2[c_r][win*64+n_r] = (1/64)*Re(IFFT2)[win][ (c_r&~31)+(n_r>>1) ][ (n_r&1)*32+(c_r&31) ]
// (x_ifft.reshape(B_,HEADS,n,hd) is a raw flat reshape — this bakes it in.
//  Formula hardware-confirmed by round-4's passing flat-read equivalent.)
// ---------------------------------------------------------------------------
__global__ __launch_bounds__(256) void k_ifft(const float* __restrict__ y2,
                                              float* __restrict__ xifft2) {
  __shared__ float T[4096];
  __shared__ float sy[64][64];
  __shared__ float sout[64][65];
  int b_ = blockIdx.x, tid = threadIdx.x;
  buildT(T, tid);
  for (int g = 0; g < 3; ++g) {
    __syncthreads();
    for (int i = tid; i < 4096; i += 256) {
      int ch = i >> 6, q = i & 63;
      sy[ch][q] = y2[(size_t)(g * 64 + ch) * NTOK + b_ * 64 + q];
    }
    __syncthreads();
    for (int i = tid; i < 4096; i += 256) {
      int ch = i >> 6, p = i & 63;
      float s = 0.0f;
      #pragma unroll
      for (int qq = 0; qq < 64; ++qq) s += T[qq * 64 + p] * sy[ch][qq];
      sout[ch][p] = s * 0.015625f;
    }
    __syncthreads();
    for (int i = tid; i < 4096; i += 256) {
      int cl = i >> 6, nr = i & 63;      // local out-channel, out-position
      int hl = cl >> 5, d = cl & 31;
      float v = sout[hl * 32 + (nr >> 1)][(nr & 1) * 32 + d];
      xifft2[(size_t)(g * 64 + cl) * NTOK + b_ * 64 + nr] = v;
    }
  }
}

// ---------------------------------------------------------------------------
// Depthwise 3x3 over the (window=512, n=64) "image" per channel of t(576,32768),
// fused with (pre-permuted) x_ifft add and q-scale.  qkvp (576, 32768).
// ---------------------------------------------------------------------------
__global__ __launch_bounds__(256) void k_dwconv(const float* __restrict__ t,
    const float* __restrict__ xifft2, const float* __restrict__ dww,
    const float* __restrict__ dwb, float* __restrict__ qkvp) {
  int o  = blockIdx.y;             // channel 0..575
  int p0 = blockIdx.x * 1024;      // position chunk
  __shared__ float st[1160];       // positions p0-64 .. p0+1088
  int tid = threadIdx.x;
  const float* trow = t + (size_t)o * NTOK;
  for (int i = tid; i < 1153; i += 256) {
    int p = p0 - 64 + i;
    st[i] = (p >= 0 && p < NTOK) ? trow[p] : 0.0f;
  }
  __syncthreads();
  float w9[9];
  #pragma unroll
  for (int u = 0; u < 9; ++u) w9[u] = dww[o * 9 + u];
  float bsv = dwb[o];
  int s = o / 192, rem = o % 192;
  const float* xrow = xifft2 + (size_t)rem * NTOK;
  const float SCALE = 0.17677669529663687f;
  #pragma unroll
  for (int it = 0; it < 4; ++it) {
    int p  = p0 + it * 256 + tid;
    int n  = p & 63;
    int li = it * 256 + tid + 64;
    float acc = bsv;
    #pragma unroll
    for (int dy = -1; dy <= 1; ++dy) {
      #pragma unroll
      for (int dx = -1; dx <= 1; ++dx) {
        int nn = n + dx;
        if (nn < 0 || nn > 63) continue;        // zero pad across n
        acc += w9[(dy + 1) * 3 + (dx + 1)] * st[li + dy * 64 + dx];
      }
    }
    float v = acc + xrow[p];
    if (s == 0) v *= SCALE;
    qkvp[(size_t)o * NTOK + p] = v;
  }
}

// ---------------------------------------------------------------------------
// Pure attention: one block per (window, head).  qkvp rows (s*192+h*32+d).
// ---------------------------------------------------------------------------
__global__ __launch_bounds__(256) void k_attn(
    const float* __restrict__ qkvp,    // (576, 32768)
    const float* __restrict__ rpb,     // (225, 6)
    float* __restrict__ aoTok)         // (32768, 192)
{
  int b_ = blockIdx.x;
  int h  = blockIdx.y;
  int tid = threadIdx.x;
  int lane = tid & 63;
  int wv = tid >> 6;
  __shared__ float sq[64][33], sk[64][33], sv[64][33];
  __shared__ float ssc[64][65];

  for (int i = tid; i < 6144; i += 256) {
    int n = i & 63;
    int row = i >> 6;            // 0..95 = s*32 + d
    int s = row >> 5, d = row & 31;
    float v = qkvp[(size_t)(s * 192 + h * 32 + d) * NTOK + b_ * 64 + n];
    if (s == 0)      sq[n][d] = v;
    else if (s == 1) sk[n][d] = v;
    else             sv[n][d] = v;
  }
  __syncthreads();
  #pragma unroll
  for (int it = 0; it < 16; ++it) {
    int i = it * 4 + wv;
    int j = lane;
    float s = 0.0f;
    #pragma unroll
    for (int d = 0; d < 32; ++d) s = fmaf(sq[i][d], sk[j][d], s);
    int dyr = (i >> 3) - (j >> 3) + 7;
    int dxr = (i & 7) - (j & 7) + 7;
    s += rpb[(dyr * 15 + dxr) * 6 + h];
    ssc[i][j] = s;
  }
  __syncthreads();
  {
    int i = tid >> 2;
    int r = tid & 3;
    float mx = -1e30f;
    #pragma unroll
    for (int jj = 0; jj < 16; ++jj) mx = fmaxf(mx, ssc[i][r * 16 + jj]);
    mx = fmaxf(mx, __shfl_xor(mx, 1));
    mx = fmaxf(mx, __shfl_xor(mx, 2));
    float sum = 0.0f;
    float ev[16];
    #pragma unroll
    for (int jj = 0; jj < 16; ++jj) {
      ev[jj] = expf(ssc[i][r * 16 + jj] - mx);
      sum += ev[jj];
    }
    sum += __shfl_xor(sum, 1);
    sum += __shfl_xor(sum, 2);
    float inv = 1.0f / sum;
    #pragma unroll
    for (int jj = 0; jj < 16; ++jj) ssc[i][r * 16 + jj] = ev[jj] * inv;
  }
  __syncthreads();
  #pragma unroll
  for (int it = 0; it < 8; ++it) {
    int idx = tid + it * 256;
    int d = idx & 31;
    int i = idx >> 5;
    float s = 0.0f;
    #pragma unroll
    for (int j = 0; j < 64; ++j) s = fmaf(ssc[i][j], sv[j][d], s);
    aoTok[((size_t)b_ * 64 + i) * CC + h * 32 + d] = s;
  }
}

// ---------------------------------------------------------------------------
// Residual + LN2 stats
// ---------------------------------------------------------------------------
__global__ __launch_bounds__(256) void k_resid(const float* __restrict__ x,
    const float* __restrict__ pout, float* __restrict__ xres,
    float* __restrict__ stats) {
  int tok = blockIdx.x * 4 + (threadIdx.x >> 6);
  int lane = threadIdx.x & 63;
  int bb = tok >> 14, l = tok & 16383;
  int hy = l >> 7, wx = l & 127;
  int col = (bb * 256 + (hy >> 3) * 16 + (wx >> 3)) * 64 + (hy & 7) * 8 + (wx & 7);
  int c = lane * 3;
  const float* xp = x + (size_t)tok * CC + c;
  const float* pp = pout + (size_t)col * CC + c;
  float v0 = xp[0] + pp[0], v1 = xp[1] + pp[1], v2 = xp[2] + pp[2];
  float* rp = xres + (size_t)tok * CC + c;
  rp[0] = v0; rp[1] = v1; rp[2] = v2;
  float s = v0 + v1 + v2;
  #pragma unroll
  for (int off = 32; off >= 1; off >>= 1) s += __shfl_xor(s, off);
  float mean = s * (1.0f / 192.0f);
  float d0 = v0 - mean, d1 = v1 - mean, d2 = v2 - mean;
  float q = d0 * d0 + d1 * d1 + d2 * d2;
  #pragma unroll
  for (int off = 32; off >= 1; off >>= 1) q += __shfl_xor(q, off);
  float rstd = rsqrtf(q * (1.0f / 192.0f) + 1e-5f);
  if (lane == 0) { stats[tok * 2] = mean; stats[tok * 2 + 1] = rstd; }
}

// LN2 apply + transpose to channel-major yT (192, 32768)
__global__ __launch_bounds__(256) void k_lnT(const float* __restrict__ xres,
    const float* __restrict__ stats, const float* __restrict__ w,
    const float* __restrict__ b, float* __restrict__ yT) {
  __shared__ float tile[32][33];
  int t0 = blockIdx.x * 32;
  int c0 = blockIdx.y * 32;
  int tid = threadIdx.x;
  #pragma unroll
  for (int i = tid; i < 1024; i += 256) {
    int row = i >> 5, col = i & 31;
    int tok = t0 + row, c = c0 + col;
    float v = xres[(size_t)tok * CC + c];
    tile[row][col] = (v - stats[tok * 2]) * stats[tok * 2 + 1] * w[c] + b[c];
  }
  __syncthreads();
  #pragma unroll
  for (int i = tid; i < 1024; i += 256) {
    int row = i >> 5, col = i & 31;
    yT[(size_t)(c0 + row) * NTOK + t0 + col] = tile[col][row];
  }
}

// ---------------------------------------------------------------------------
// Fused FFN middle (chunked, 64-row strip). ff0 (1536, 68*128), x1cat (1536, 8192)
// ---------------------------------------------------------------------------
__global__ __launch_bounds__(256) void k_ffmid(const float* __restrict__ ff0,
    const float* __restrict__ dw3w, const float* __restrict__ dw5w,
    const float* __restrict__ dw31w, const float* __restrict__ dw51w,
    float* __restrict__ x1cat, int r0, int row0) {
  int m = blockIdx.y;
  int ty0 = r0 + (blockIdx.x >> 3) * 16, tx0 = (blockIdx.x & 7) * 16;
  __shared__ float sA[2][24][24];
  __shared__ float aloc[2][20][20];
  __shared__ float bloc[2][20][20];
  int tid = threadIdx.x;
  for (int i = tid; i < 576; i += 256) {
    int yy = i / 24, xx = i % 24;
    int gy = ty0 - 4 + yy, gx = tx0 - 4 + xx;
    bool ok = (gy >= 0 && gy < HHH && gx >= 0 && gx < WWW);
    size_t base = (size_t)(2 * m) * 8704 + (size_t)(ok ? ((gy - row0) * WWW + gx) : 0);
    sA[0][yy][xx] = ok ? ff0[base] : 0.0f;
    sA[1][yy][xx] = ok ? ff0[base + 8704] : 0.0f;
  }
  __syncthreads();
  for (int i = tid; i < 400; i += 256) {
    int yy = i / 20, xx = i % 20;
    int gy = ty0 - 2 + yy, gx = tx0 - 2 + xx;
    bool in = (gy >= 0 && gy < HHH && gx >= 0 && gx < WWW);
    #pragma unroll
    for (int kk = 0; kk < 2; ++kk) {
      int ch = 2 * m + kk;
      const float* w3 = dw3w + ch * 9;
      const float* w5 = dw5w + ch * 25;
      float s3 = 0.0f, s5 = 0.0f;
      #pragma unroll
      for (int dy = 0; dy < 5; ++dy)
        #pragma unroll
        for (int dx = 0; dx < 5; ++dx) {
          float vv = sA[kk][yy + dy][xx + dx];
          s5 += w5[dy * 5 + dx] * vv;
          if (dy >= 1 && dy <= 3 && dx >= 1 && dx <= 3)
            s3 += w3[(dy - 1) * 3 + (dx - 1)] * vv;
        }
      aloc[kk][yy][xx] = in ? fmaxf(s3, 0.0f) : 0.0f;
      bloc[kk][yy][xx] = in ? fmaxf(s5, 0.0f) : 0.0f;
    }
  }
  __syncthreads();
  int oy = tid >> 4, ox = tid & 15;
  bool small = (m < 384);
  const float* kA = small ? (dw31w + m * 18)         : (dw51w + (m - 384) * 50);
  const float* kB = small ? (dw31w + (m + 384) * 18) : (dw51w + m * 50);
  int ochA = small ? m       : m + 384;
  int ochB = small ? m + 384 : 768 + m;
  int ksz = small ? 3 : 5;
  int r   = small ? 1 : 2;
  float sAo = 0.0f, sBo = 0.0f;
  for (int kk2 = 0; kk2 < 2; ++kk2) {
    for (int dy = -r; dy <= r; ++dy)
      for (int dx = -r; dx <= r; ++dx) {
        int widx = kk2 * ksz * ksz + (dy + r) * ksz + (dx + r);
        sAo += kA[widx] * aloc[kk2][oy + 2 + dy][ox + 2 + dx];
        sBo += kB[widx] * bloc[kk2][oy + 2 + dy][ox + 2 + dx];
      }
  }
  size_t px = (size_t)(ty0 - r0 + oy) * WWW + tx0 + ox;
  x1cat[(size_t)ochA * 8192 + px] = gelu_f(sAo);
  x1cat[(size_t)ochB * 8192 + px] = gelu_f(sBo);
}

// ---------------------------------------------------------------------------
extern "C" void kernel_launch(void* const* d_in, const int* in_sizes, int n_in,
                              void* d_out, int out_size, void* d_ws, size_t ws_size,
                              hipStream_t stream) {
  (void)in_sizes; (void)n_in;
  const float* x      = (const float*)d_in[0];
  const float* ln1w   = (const float*)d_in[1];
  const float* ln1b   = (const float*)d_in[2];
  const float* rpb    = (const float*)d_in[3];
  const float* qkvw   = (const float*)d_in[4];
  const float* qkvb   = (const float*)d_in[5];
  const float* qkvdww = (const float*)d_in[6];
  const float* qkvdwb = (const float*)d_in[7];
  const float* q1w    = (const float*)d_in[8];
  const float* q2w    = (const float*)d_in[9];
  const float* projw  = (const float*)d_in[10];
  const float* projb  = (const float*)d_in[11];
  const float* ln2w   = (const float*)d_in[12];
  const float* ln2b   = (const float*)d_in[13];
  const float* pinw   = (const float*)d_in[14];
  const float* dw3w   = (const float*)d_in[15];
  const float* dw5w   = (const float*)d_in[16];
  const float* dw31w  = (const float*)d_in[17];
  const float* dw51w  = (const float*)d_in[18];
  const float* poutw  = (const float*)d_in[19];
  float* out = (float*)d_out;
  float* ws  = (float*)d_ws;

  const size_t SZ = 6291456;            // 32768 * 192 floats (24 MiB)
  const size_t NEED = 7 * SZ * 4;       // 168 MiB (proven available in r4)
  if (ws_size < NEED) {
    hipMemcpyAsync(d_out, d_in[0], (size_t)out_size * sizeof(float),
                   hipMemcpyDeviceToDevice, stream);
    return;
  }

  // Slot overlay (stream-order lifetimes):
  float* xw     = ws + SZ;                    // slot1
  float* t      = ws + 4 * SZ;                // slots 4-6
  float* xfftT  = ws + 2 * SZ;                // slot2
  float* y1     = ws + SZ;                    // slot1 (xw dead after fft)
  float* y2     = ws + 2 * SZ;                // slot2 (xfftT dead after q1)
  float* xifft2 = ws + 3 * SZ;                // slot3
  float* qkvp   = ws;                         // slots 0-2
  float* aoTok  = ws + 3 * SZ;                // slot3 (xifft2 dead after dwconv)
  float* projo  = ws + 4 * SZ;                // slot4 (t dead after dwconv)
  float* xres   = ws;                         // slot0 (qkvp dead after attn)
  float* yT     = ws + SZ;                    // slot1
  float* ff0    = ws + 2 * SZ;                // 1536 x 8704
  float* x1cat  = ws + 2 * SZ + 15728640;     // 1536 x 8192
  float* stats  = ws + 7 * SZ - 65536;        // tail of slot6

  // --- attention phase ---
  k_ln1<<<8192, 256, 0, stream>>>(x, ln1w, ln1b, xw);
  k_gemmT<64, 128, 4, 8><<<dim3(256, 9), 256, 0, stream>>>(qkvw, xw, t, qkvb,
      nullptr, 192, 192, 192, 32768, 1, 1, 0);
  k_fft<<<512, 256, 0, stream>>>(xw, xfftT);
  k_gemmT<64, 128, 4, 8><<<dim3(256, 3), 256, 0, stream>>>(q1w, xfftT, y1,
      nullptr, nullptr, 192, 192, 32768, 32768, 0, 0, 1);
  k_gemmT<64, 128, 4, 8><<<dim3(256, 3), 256, 0, stream>>>(q2w, y1, y2,
      nullptr, nullptr, 192, 192, 32768, 32768, 0, 0, 0);
  k_ifft<<<512, 256, 0, stream>>>(y2, xifft2);
  k_dwconv<<<dim3(32, 576), 256, 0, stream>>>(t, xifft2, qkvdww, qkvdwb, qkvp);
  k_attn<<<dim3(512, 6), 256, 0, stream>>>(qkvp, rpb, aoTok);
  k_gemmT<128, 64, 8, 4><<<dim3(3, 256), 256, 0, stream>>>(aoTok, projw, projo,
      projb, nullptr, 192, 192, 192, 192, 1, 2, 0);
  k_resid<<<8192, 256, 0, stream>>>(x, projo, xres, stats);
  k_lnT<<<dim3(1024, 6), 256, 0, stream>>>(xres, stats, ln2w, ln2b, yT);

  // --- FFN phase: per (batch, half-image strip) ---
  for (int bb = 0; bb < 2; ++bb) {
    for (int ci = 0; ci < 2; ++ci) {
      int r0   = ci * 64;
      int row0 = (ci == 0) ? 0 : 60;
      k_gemmT<128, 128, 8, 8><<<dim3(68, 12), 256, 0, stream>>>(pinw,
          yT + bb * 16384 + row0 * WWW, ff0, nullptr, nullptr,
          192, 192, 32768, 8704, 0, 0, 0);
      k_ffmid<<<dim3(32, 768), 256, 0, stream>>>(ff0, dw3w, dw5w, dw31w, dw51w,
          x1cat, r0, row0);
      k_gemmT<64, 128, 4, 8><<<dim3(64, 3), 256, 0, stream>>>(poutw, x1cat,
          out + (size_t)bb * 3145728 + r0 * WWW,
          nullptr, xres + (size_t)bb * 3145728 + r0 * WWW,
          1536, 1536, 8192, 16384, 0, 0, 0);
    }
  }
}

// Round 14
// 1805.450 us; speedup vs baseline: 1.3910x; 1.1507x over previous
//
#include <hip/hip_runtime.h>
#include <cstdint>

// Problem constants
#define CC   192          // channels
#define NTOK 32768        // B * H * W  (= 512 windows * 64)
#define HHH  128
#define WWW  128

__device__ __forceinline__ float gelu_f(float x) {
  return 0.5f * x * (1.0f + erff(x * 0.70710678118654752440f));
}

// ---------------------------------------------------------------------------
// K1: LayerNorm1 + window partition.  x (B,L,C) -> xw (512 windows, 64, 192)
// ---------------------------------------------------------------------------
__global__ __launch_bounds__(256) void k_ln1(const float* __restrict__ x,
    const float* __restrict__ w, const float* __restrict__ b,
    float* __restrict__ xw) {
  int tok  = blockIdx.x * 4 + (threadIdx.x >> 6);
  int lane = threadIdx.x & 63;
  const float* xp = x + (size_t)tok * CC + lane * 3;
  float v0 = xp[0], v1 = xp[1], v2 = xp[2];
  float s = v0 + v1 + v2;
  #pragma unroll
  for (int off = 32; off >= 1; off >>= 1) s += __shfl_xor(s, off);
  float mean = s * (1.0f / 192.0f);
  float d0 = v0 - mean, d1 = v1 - mean, d2 = v2 - mean;
  float q = d0 * d0 + d1 * d1 + d2 * d2;
  #pragma unroll
  for (int off = 32; off >= 1; off >>= 1) q += __shfl_xor(q, off);
  float rstd = rsqrtf(q * (1.0f / 192.0f) + 1e-5f);
  int bb = tok >> 14, l = tok & 16383;
  int hy = l >> 7, wx = l & 127;
  int win = bb * 256 + (hy >> 3) * 16 + (wx >> 3);
  int n   = (hy & 7) * 8 + (wx & 7);
  int c = lane * 3;
  float* op = xw + ((size_t)win * 64 + n) * CC + c;
  op[0] = d0 * rstd * w[c]     + b[c];
  op[1] = d1 * rstd * w[c + 1] + b[c + 1];
  op[2] = d2 * rstd * w[c + 2] + b[c + 2];
}

// ---------------------------------------------------------------------------
// Templated fp32 tiled GEMM: C[M,N] = act(A[M,K]*B[K,N] + bias) [+ res]
// BM x BN block tile, TM x TN per thread, 256 threads, K-step 16.
// A row-major (lda). B row-major KxN (ldb) or, if btrans, stored NxK.
// biasmode: 0 none, 1 per-row(M), 2 per-col(N). act: 0 none, 1 gelu.
// ---------------------------------------------------------------------------
template<int BM, int BN, int TM, int TN>
__global__ __launch_bounds__(256) void k_gemmT(const float* __restrict__ A,
    const float* __restrict__ B, float* __restrict__ Cmat,
    const float* __restrict__ bias, const float* __restrict__ res,
    int K, int lda, int ldb, int ldc, int btrans, int biasmode, int act) {
  __shared__ alignas(16) float As[16][BM + 4];
  __shared__ alignas(16) float Bs[16][BN + 4];
  int m0 = blockIdx.y * BM, n0 = blockIdx.x * BN;
  int tid = threadIdx.x;
  constexpr int NTX = BN / TN;
  int tx = tid % NTX, ty = tid / NTX;
  float acc[TM][TN] = {};
  for (int k0 = 0; k0 < K; k0 += 16) {
    #pragma unroll
    for (int i = tid; i < BM * 4; i += 256) {
      int mm = i >> 2, kk = (i & 3) * 4;
      float4 v = *reinterpret_cast<const float4*>(&A[(size_t)(m0 + mm) * lda + k0 + kk]);
      As[kk][mm] = v.x; As[kk + 1][mm] = v.y; As[kk + 2][mm] = v.z; As[kk + 3][mm] = v.w;
    }
    if (btrans) {
      #pragma unroll
      for (int i = tid; i < BN * 4; i += 256) {
        int nn = i >> 2, kk = (i & 3) * 4;
        float4 v = *reinterpret_cast<const float4*>(&B[(size_t)(n0 + nn) * ldb + k0 + kk]);
        Bs[kk][nn] = v.x; Bs[kk + 1][nn] = v.y; Bs[kk + 2][nn] = v.z; Bs[kk + 3][nn] = v.w;
      }
    } else {
      #pragma unroll
      for (int i = tid; i < BN * 4; i += 256) {
        int kk = i / (BN / 4), nn4 = (i % (BN / 4)) * 4;
        *reinterpret_cast<float4*>(&Bs[kk][nn4]) =
            *reinterpret_cast<const float4*>(&B[(size_t)(k0 + kk) * ldb + n0 + nn4]);
      }
    }
    __syncthreads();
    #pragma unroll
    for (int k = 0; k < 16; ++k) {
      float av[TM], bv[TN];
      #pragma unroll
      for (int u = 0; u < TM; u += 4)
        *reinterpret_cast<float4*>(&av[u]) = *reinterpret_cast<const float4*>(&As[k][ty * TM + u]);
      #pragma unroll
      for (int u = 0; u < TN; u += 4)
        *reinterpret_cast<float4*>(&bv[u]) = *reinterpret_cast<const float4*>(&Bs[k][tx * TN + u]);
      #pragma unroll
      for (int im = 0; im < TM; ++im)
        #pragma unroll
        for (int jn = 0; jn < TN; ++jn)
          acc[im][jn] = fmaf(av[im], bv[jn], acc[im][jn]);
    }
    __syncthreads();
  }
  #pragma unroll
  for (int im = 0; im < TM; ++im) {
    int cm = m0 + ty * TM + im;
    float bm = (biasmode == 1) ? bias[cm] : 0.0f;
    #pragma unroll
    for (int jn = 0; jn < TN; jn += 4) {
      int cn = n0 + tx * TN + jn;
      float4 r4 = make_float4(0.f, 0.f, 0.f, 0.f);
      if (res) r4 = *reinterpret_cast<const float4*>(&res[(size_t)cm * ldc + cn]);
      float vv[4];
      #pragma unroll
      for (int u = 0; u < 4; ++u) {
        float t = acc[im][jn + u] + bm;
        if (biasmode == 2) t += bias[cn + u];
        if (act == 1) t = gelu_f(t);
        vv[u] = t;
      }
      float4 o;
      o.x = vv[0] + r4.x; o.y = vv[1] + r4.y; o.z = vv[2] + r4.z; o.w = vv[3] + r4.w;
      *reinterpret_cast<float4*>(&Cmat[(size_t)cm * ldc + cn]) = o;
    }
  }
}

// ---------------------------------------------------------------------------
// Split-K GEMM partial: P[kc][M][N] += A[M, kbeg:kbeg+KC] * B[kbeg:.., N]
// A row-major (lda); B row-major KxN (ldb).  blockIdx.z = K-chunk index.
// Fixes the 192-block occupancy collapse of the pout GEMM (r10 counters:
// 8.7% occupancy, 1 wave/SIMD, VALUBusy 19.6%).
// ---------------------------------------------------------------------------
template<int BM, int BN, int TM, int TN>
__global__ __launch_bounds__(256) void k_gemmSK(const float* __restrict__ A,
    const float* __restrict__ B, float* __restrict__ P,
    int KC, int lda, int ldb, int M, int N) {
  __shared__ alignas(16) float As[16][BM + 4];
  __shared__ alignas(16) float Bs[16][BN + 4];
  int m0 = blockIdx.y * BM, n0 = blockIdx.x * BN;
  int kbeg = blockIdx.z * KC;
  int tid = threadIdx.x;
  constexpr int NTX = BN / TN;
  int tx = tid % NTX, ty = tid / NTX;
  float acc[TM][TN] = {};
  for (int k0 = kbeg; k0 < kbeg + KC; k0 += 16) {
    #pragma unroll
    for (int i = tid; i < BM * 4; i += 256) {
      int mm = i >> 2, kk = (i & 3) * 4;
      float4 v = *reinterpret_cast<const float4*>(&A[(size_t)(m0 + mm) * lda + k0 + kk]);
      As[kk][mm] = v.x; As[kk + 1][mm] = v.y; As[kk + 2][mm] = v.z; As[kk + 3][mm] = v.w;
    }
    #pragma unroll
    for (int i = tid; i < BN * 4; i += 256) {
      int kk = i / (BN / 4), nn4 = (i % (BN / 4)) * 4;
      *reinterpret_cast<float4*>(&Bs[kk][nn4]) =
          *reinterpret_cast<const float4*>(&B[(size_t)(k0 + kk) * ldb + n0 + nn4]);
    }
    __syncthreads();
    #pragma unroll
    for (int k = 0; k < 16; ++k) {
      float av[TM], bv[TN];
      #pragma unroll
      for (int u = 0; u < TM; u += 4)
        *reinterpret_cast<float4*>(&av[u]) = *reinterpret_cast<const float4*>(&As[k][ty * TM + u]);
      #pragma unroll
      for (int u = 0; u < TN; u += 4)
        *reinterpret_cast<float4*>(&bv[u]) = *reinterpret_cast<const float4*>(&Bs[k][tx * TN + u]);
      #pragma unroll
      for (int im = 0; im < TM; ++im)
        #pragma unroll
        for (int jn = 0; jn < TN; ++jn)
          acc[im][jn] = fmaf(av[im], bv[jn], acc[im][jn]);
    }
    __syncthreads();
  }
  float* Pp = P + (size_t)blockIdx.z * M * N;
  #pragma unroll
  for (int im = 0; im < TM; ++im) {
    int cm = m0 + ty * TM + im;
    #pragma unroll
    for (int jn = 0; jn < TN; jn += 4) {
      int cn = n0 + tx * TN + jn;
      float4 o;
      o.x = acc[im][jn]; o.y = acc[im][jn + 1];
      o.z = acc[im][jn + 2]; o.w = acc[im][jn + 3];
      *reinterpret_cast<float4*>(&Pp[(size_t)cm * N + cn]) = o;
    }
  }
}

// reduce 3 K-chunk partials + residual -> out (ldo-strided rows of N cols)
__global__ __launch_bounds__(256) void k_red3(const float* __restrict__ P,
    const float* __restrict__ res, float* __restrict__ out, int N, int ldo) {
  int i = blockIdx.x * 256 + threadIdx.x;    // float4 index over 192*N/4
  size_t base = (size_t)i * 4;
  int cm = (int)(base / N);
  int cn = (int)(base - (size_t)cm * N);
  const size_t CH = (size_t)192 * N;
  float4 a = *reinterpret_cast<const float4*>(&P[base]);
  float4 b = *reinterpret_cast<const float4*>(&P[base + CH]);
  float4 c = *reinterpret_cast<const float4*>(&P[base + 2 * CH]);
  float4 r = *reinterpret_cast<const float4*>(&res[(size_t)cm * ldo + cn]);
  float4 o;
  o.x = a.x + b.x + c.x + r.x;
  o.y = a.y + b.y + c.y + r.y;
  o.z = a.z + b.z + c.z + r.z;
  o.w = a.w + b.w + c.w + r.w;
  *reinterpret_cast<float4*>(&out[(size_t)cm * ldo + cn]) = o;
}

// ---------------------------------------------------------------------------
// 8x8 real-FFT basis (symmetric; serves Re(FFT) and Re(IFFT))
// ---------------------------------------------------------------------------
__device__ __forceinline__ void buildT(float* T, int tid) {
  const float R2 = 0.70710678118654752440f;
  for (int i = tid; i < 4096; i += 256) {
    int p = i >> 6, qq = i & 63;
    int m = ((p >> 3) * (qq >> 3) + (p & 7) * (qq & 7)) & 7;
    float c;
    if (m == 0) c = 1.0f;
    else if (m == 4) c = -1.0f;
    else if (m == 2 || m == 6) c = 0.0f;
    else if (m == 1 || m == 7) c = R2;
    else c = -R2;
    T[i] = c;
  }
}

// xw (win,64,192) -> xfftT (192, 32768) : Re(FFT2)
__global__ __launch_bounds__(256) void k_fft(const float* __restrict__ xw,
                                             float* __restrict__ xfftT) {
  __shared__ float T[4096];
  __shared__ float sw[64][96];
  int b_ = blockIdx.x, tid = threadIdx.x;
  buildT(T, tid);
  for (int half = 0; half < 2; ++half) {
    __syncthreads();
    for (int i = tid; i < 6144; i += 256) {
      int q = i / 96, ch = i % 96;
      sw[q][ch] = xw[(size_t)b_ * 12288 + q * 192 + half * 96 + ch];
    }
    __syncthreads();
    for (int idx = tid; idx < 6144; idx += 256) {
      int ch = idx >> 6, p = idx & 63;
      float s = 0.0f;
      #pragma unroll
      for (int qq = 0; qq < 64; ++qq) s += T[qq * 64 + p] * sw[qq][ch];
      xfftT[(size_t)(half * 96 + ch) * NTOK + b_ * 64 + p] = s;
    }
  }
}

// ---------------------------------------------------------------------------
// y2 (192,32768) -> xifft2 (192, 32768) channel-major of the RESHAPED tensor:
// xifft2[c_r][win*64+n_r] = (1/64)*Re(IFFT2)[win][ (c_r&~31)+(n_r>>1) ][ (n_r&1)*32+(c_r&31) ]
// (hardware-confirmed formula via round-4's passing flat-read equivalent)
// ---------------------------------------------------------------------------
__global__ __launch_bounds__(256) void k_ifft(const float* __restrict__ y2,
                                              float* __restrict__ xifft2) {
  __shared__ float T[4096];
  __shared__ float sy[64][64];
  __shared__ float sout[64][65];
  int b_ = blockIdx.x, tid = threadIdx.x;
  buildT(T, tid);
  for (int g = 0; g < 3; ++g) {
    __syncthreads();
    for (int i = tid; i < 4096; i += 256) {
      int ch = i >> 6, q = i & 63;
      sy[ch][q] = y2[(size_t)(g * 64 + ch) * NTOK + b_ * 64 + q];
    }
    __syncthreads();
    for (int i = tid; i < 4096; i += 256) {
      int ch = i >> 6, p = i & 63;
      float s = 0.0f;
      #pragma unroll
      for (int qq = 0; qq < 64; ++qq) s += T[qq * 64 + p] * sy[ch][qq];
      sout[ch][p] = s * 0.015625f;
    }
    __syncthreads();
    for (int i = tid; i < 4096; i += 256) {
      int cl = i >> 6, nr = i & 63;
      int hl = cl >> 5, d = cl & 31;
      float v = sout[hl * 32 + (nr >> 1)][(nr & 1) * 32 + d];
      xifft2[(size_t)(g * 64 + cl) * NTOK + b_ * 64 + nr] = v;
    }
  }
}

// ---------------------------------------------------------------------------
// Depthwise 3x3 over (window, n) per channel of t(576,32768), fused with
// (pre-permuted) x_ifft add and q-scale.  qkvp (576, 32768).
// ---------------------------------------------------------------------------
__global__ __launch_bounds__(256) void k_dwconv(const float* __restrict__ t,
    const float* __restrict__ xifft2, const float* __restrict__ dww,
    const float* __restrict__ dwb, float* __restrict__ qkvp) {
  int o  = blockIdx.y;
  int p0 = blockIdx.x * 1024;
  __shared__ float st[1160];
  int tid = threadIdx.x;
  const float* trow = t + (size_t)o * NTOK;
  for (int i = tid; i < 1153; i += 256) {
    int p = p0 - 64 + i;
    st[i] = (p >= 0 && p < NTOK) ? trow[p] : 0.0f;
  }
  __syncthreads();
  float w9[9];
  #pragma unroll
  for (int u = 0; u < 9; ++u) w9[u] = dww[o * 9 + u];
  float bsv = dwb[o];
  int s = o / 192, rem = o % 192;
  const float* xrow = xifft2 + (size_t)rem * NTOK;
  const float SCALE = 0.17677669529663687f;
  #pragma unroll
  for (int it = 0; it < 4; ++it) {
    int p  = p0 + it * 256 + tid;
    int n  = p & 63;
    int li = it * 256 + tid + 64;
    float acc = bsv;
    #pragma unroll
    for (int dy = -1; dy <= 1; ++dy) {
      #pragma unroll
      for (int dx = -1; dx <= 1; ++dx) {
        int nn = n + dx;
        if (nn < 0 || nn > 63) continue;
        acc += w9[(dy + 1) * 3 + (dx + 1)] * st[li + dy * 64 + dx];
      }
    }
    float v = acc + xrow[p];
    if (s == 0) v *= SCALE;
    qkvp[(size_t)o * NTOK + p] = v;
  }
}

// ---------------------------------------------------------------------------
// Pure attention: one block per (window, head).
// ---------------------------------------------------------------------------
__global__ __launch_bounds__(256) void k_attn(
    const float* __restrict__ qkvp, const float* __restrict__ rpb,
    float* __restrict__ aoTok) {
  int b_ = blockIdx.x;
  int h  = blockIdx.y;
  int tid = threadIdx.x;
  int lane = tid & 63;
  int wv = tid >> 6;
  __shared__ float sq[64][33], sk[64][33], sv[64][33];
  __shared__ float ssc[64][65];

  for (int i = tid; i < 6144; i += 256) {
    int n = i & 63;
    int row = i >> 6;
    int s = row >> 5, d = row & 31;
    float v = qkvp[(size_t)(s * 192 + h * 32 + d) * NTOK + b_ * 64 + n];
    if (s == 0)      sq[n][d] = v;
    else if (s == 1) sk[n][d] = v;
    else             sv[n][d] = v;
  }
  __syncthreads();
  #pragma unroll
  for (int it = 0; it < 16; ++it) {
    int i = it * 4 + wv;
    int j = lane;
    float s = 0.0f;
    #pragma unroll
    for (int d = 0; d < 32; ++d) s = fmaf(sq[i][d], sk[j][d], s);
    int dyr = (i >> 3) - (j >> 3) + 7;
    int dxr = (i & 7) - (j & 7) + 7;
    s += rpb[(dyr * 15 + dxr) * 6 + h];
    ssc[i][j] = s;
  }
  __syncthreads();
  {
    int i = tid >> 2;
    int r = tid & 3;
    float mx = -1e30f;
    #pragma unroll
    for (int jj = 0; jj < 16; ++jj) mx = fmaxf(mx, ssc[i][r * 16 + jj]);
    mx = fmaxf(mx, __shfl_xor(mx, 1));
    mx = fmaxf(mx, __shfl_xor(mx, 2));
    float sum = 0.0f;
    float ev[16];
    #pragma unroll
    for (int jj = 0; jj < 16; ++jj) {
      ev[jj] = expf(ssc[i][r * 16 + jj] - mx);
      sum += ev[jj];
    }
    sum += __shfl_xor(sum, 1);
    sum += __shfl_xor(sum, 2);
    float inv = 1.0f / sum;
    #pragma unroll
    for (int jj = 0; jj < 16; ++jj) ssc[i][r * 16 + jj] = ev[jj] * inv;
  }
  __syncthreads();
  #pragma unroll
  for (int it = 0; it < 8; ++it) {
    int idx = tid + it * 256;
    int d = idx & 31;
    int i = idx >> 5;
    float s = 0.0f;
    #pragma unroll
    for (int j = 0; j < 64; ++j) s = fmaf(ssc[i][j], sv[j][d], s);
    aoTok[((size_t)b_ * 64 + i) * CC + h * 32 + d] = s;
  }
}

// ---------------------------------------------------------------------------
// Residual + LN2 stats
// ---------------------------------------------------------------------------
__global__ __launch_bounds__(256) void k_resid(const float* __restrict__ x,
    const float* __restrict__ pout, float* __restrict__ xres,
    float* __restrict__ stats) {
  int tok = blockIdx.x * 4 + (threadIdx.x >> 6);
  int lane = threadIdx.x & 63;
  int bb = tok >> 14, l = tok & 16383;
  int hy = l >> 7, wx = l & 127;
  int col = (bb * 256 + (hy >> 3) * 16 + (wx >> 3)) * 64 + (hy & 7) * 8 + (wx & 7);
  int c = lane * 3;
  const float* xp = x + (size_t)tok * CC + c;
  const float* pp = pout + (size_t)col * CC + c;
  float v0 = xp[0] + pp[0], v1 = xp[1] + pp[1], v2 = xp[2] + pp[2];
  float* rp = xres + (size_t)tok * CC + c;
  rp[0] = v0; rp[1] = v1; rp[2] = v2;
  float s = v0 + v1 + v2;
  #pragma unroll
  for (int off = 32; off >= 1; off >>= 1) s += __shfl_xor(s, off);
  float mean = s * (1.0f / 192.0f);
  float d0 = v0 - mean, d1 = v1 - mean, d2 = v2 - mean;
  float q = d0 * d0 + d1 * d1 + d2 * d2;
  #pragma unroll
  for (int off = 32; off >= 1; off >>= 1) q += __shfl_xor(q, off);
  float rstd = rsqrtf(q * (1.0f / 192.0f) + 1e-5f);
  if (lane == 0) { stats[tok * 2] = mean; stats[tok * 2 + 1] = rstd; }
}

// LN2 apply + transpose to channel-major yT (192, 32768)
__global__ __launch_bounds__(256) void k_lnT(const float* __restrict__ xres,
    const float* __restrict__ stats, const float* __restrict__ w,
    const float* __restrict__ b, float* __restrict__ yT) {
  __shared__ float tile[32][33];
  int t0 = blockIdx.x * 32;
  int c0 = blockIdx.y * 32;
  int tid = threadIdx.x;
  #pragma unroll
  for (int i = tid; i < 1024; i += 256) {
    int row = i >> 5, col = i & 31;
    int tok = t0 + row, c = c0 + col;
    float v = xres[(size_t)tok * CC + c];
    tile[row][col] = (v - stats[tok * 2]) * stats[tok * 2 + 1] * w[c] + b[c];
  }
  __syncthreads();
  #pragma unroll
  for (int i = tid; i < 1024; i += 256) {
    int row = i >> 5, col = i & 31;
    yT[(size_t)(c0 + row) * NTOK + t0 + col] = tile[col][row];
  }
}

// ---------------------------------------------------------------------------
// Fused FFN middle (chunked, 64-row strip). ff0 (1536, 68*128), x1cat (1536, 8192)
// ---------------------------------------------------------------------------
__global__ __launch_bounds__(256) void k_ffmid(const float* __restrict__ ff0,
    const float* __restrict__ dw3w, const float* __restrict__ dw5w,
    const float* __restrict__ dw31w, const float* __restrict__ dw51w,
    float* __restrict__ x1cat, int r0, int row0) {
  int m = blockIdx.y;
  int ty0 = r0 + (blockIdx.x >> 3) * 16, tx0 = (blockIdx.x & 7) * 16;
  __shared__ float sA[2][24][24];
  __shared__ float aloc[2][20][20];
  __shared__ float bloc[2][20][20];
  int tid = threadIdx.x;
  for (int i = tid; i < 576; i += 256) {
    int yy = i / 24, xx = i % 24;
    int gy = ty0 - 4 + yy, gx = tx0 - 4 + xx;
    bool ok = (gy >= 0 && gy < HHH && gx >= 0 && gx < WWW);
    size_t base = (size_t)(2 * m) * 8704 + (size_t)(ok ? ((gy - row0) * WWW + gx) : 0);
    sA[0][yy][xx] = ok ? ff0[base] : 0.0f;
    sA[1][yy][xx] = ok ? ff0[base + 8704] : 0.0f;
  }
  __syncthreads();
  for (int i = tid; i < 400; i += 256) {
    int yy = i / 20, xx = i % 20;
    int gy = ty0 - 2 + yy, gx = tx0 - 2 + xx;
    bool in = (gy >= 0 && gy < HHH && gx >= 0 && gx < WWW);
    #pragma unroll
    for (int kk = 0; kk < 2; ++kk) {
      int ch = 2 * m + kk;
      const float* w3 = dw3w + ch * 9;
      const float* w5 = dw5w + ch * 25;
      float s3 = 0.0f, s5 = 0.0f;
      #pragma unroll
      for (int dy = 0; dy < 5; ++dy)
        #pragma unroll
        for (int dx = 0; dx < 5; ++dx) {
          float vv = sA[kk][yy + dy][xx + dx];
          s5 += w5[dy * 5 + dx] * vv;
          if (dy >= 1 && dy <= 3 && dx >= 1 && dx <= 3)
            s3 += w3[(dy - 1) * 3 + (dx - 1)] * vv;
        }
      aloc[kk][yy][xx] = in ? fmaxf(s3, 0.0f) : 0.0f;
      bloc[kk][yy][xx] = in ? fmaxf(s5, 0.0f) : 0.0f;
    }
  }
  __syncthreads();
  int oy = tid >> 4, ox = tid & 15;
  bool small = (m < 384);
  const float* kA = small ? (dw31w + m * 18)         : (dw51w + (m - 384) * 50);
  const float* kB = small ? (dw31w + (m + 384) * 18) : (dw51w + m * 50);
  int ochA = small ? m       : m + 384;
  int ochB = small ? m + 384 : 768 + m;
  int ksz = small ? 3 : 5;
  int r   = small ? 1 : 2;
  float sAo = 0.0f, sBo = 0.0f;
  for (int kk2 = 0; kk2 < 2; ++kk2) {
    for (int dy = -r; dy <= r; ++dy)
      for (int dx = -r; dx <= r; ++dx) {
        int widx = kk2 * ksz * ksz + (dy + r) * ksz + (dx + r);
        sAo += kA[widx] * aloc[kk2][oy + 2 + dy][ox + 2 + dx];
        sBo += kB[widx] * bloc[kk2][oy + 2 + dy][ox + 2 + dx];
      }
  }
  size_t px = (size_t)(ty0 - r0 + oy) * WWW + tx0 + ox;
  x1cat[(size_t)ochA * 8192 + px] = gelu_f(sAo);
  x1cat[(size_t)ochB * 8192 + px] = gelu_f(sBo);
}

// ---------------------------------------------------------------------------
extern "C" void kernel_launch(void* const* d_in, const int* in_sizes, int n_in,
                              void* d_out, int out_size, void* d_ws, size_t ws_size,
                              hipStream_t stream) {
  (void)in_sizes; (void)n_in;
  const float* x      = (const float*)d_in[0];
  const float* ln1w   = (const float*)d_in[1];
  const float* ln1b   = (const float*)d_in[2];
  const float* rpb    = (const float*)d_in[3];
  const float* qkvw   = (const float*)d_in[4];
  const float* qkvb   = (const float*)d_in[5];
  const float* qkvdww = (const float*)d_in[6];
  const float* qkvdwb = (const float*)d_in[7];
  const float* q1w    = (const float*)d_in[8];
  const float* q2w    = (const float*)d_in[9];
  const float* projw  = (const float*)d_in[10];
  const float* projb  = (const float*)d_in[11];
  const float* ln2w   = (const float*)d_in[12];
  const float* ln2b   = (const float*)d_in[13];
  const float* pinw   = (const float*)d_in[14];
  const float* dw3w   = (const float*)d_in[15];
  const float* dw5w   = (const float*)d_in[16];
  const float* dw31w  = (const float*)d_in[17];
  const float* dw51w  = (const float*)d_in[18];
  const float* poutw  = (const float*)d_in[19];
  float* out = (float*)d_out;
  float* ws  = (float*)d_ws;

  const size_t SZ = 6291456;            // 32768 * 192 floats (24 MiB)
  const size_t NEED = 7 * SZ * 4;       // 168 MiB (proven available in r4/r10)
  if (ws_size < NEED) {
    hipMemcpyAsync(d_out, d_in[0], (size_t)out_size * sizeof(float),
                   hipMemcpyDeviceToDevice, stream);
    return;
  }

  // Slot overlay (stream-order lifetimes):
  float* xw     = ws + SZ;                    // slot1
  float* t      = ws + 4 * SZ;                // slots 4-6
  float* xfftT  = ws + 2 * SZ;                // slot2
  float* y1     = ws + SZ;                    // slot1 (xw dead after fft)
  float* y2     = ws + 2 * SZ;                // slot2 (xfftT dead after q1)
  float* xifft2 = ws + 3 * SZ;                // slot3
  float* qkvp   = ws;                         // slots 0-2
  float* aoTok  = ws + 3 * SZ;                // slot3 (xifft2 dead after dwconv)
  float* projo  = ws + 4 * SZ;                // slot4 (t dead after dwconv)
  float* xres   = ws;                         // slot0 (qkvp dead after attn)
  float* yT     = ws + SZ;                    // slot1
  float* ff0    = ws + 2 * SZ;                // [12.58M, 25.95M) floats
  float* x1cat  = ws + 2 * SZ + 13369344;     // [25.95M, 38.53M)
  float* psum   = ws + 38535168;              // [38.53M, 43.25M) 3x192x8192
  float* stats  = ws + 7 * SZ - 65536;        // tail of slot6 (dead before psum use)

  // --- attention phase ---
  k_ln1<<<8192, 256, 0, stream>>>(x, ln1w, ln1b, xw);
  k_gemmT<64, 128, 4, 8><<<dim3(256, 9), 256, 0, stream>>>(qkvw, xw, t, qkvb,
      nullptr, 192, 192, 192, 32768, 1, 1, 0);
  k_fft<<<512, 256, 0, stream>>>(xw, xfftT);
  k_gemmT<64, 128, 4, 8><<<dim3(256, 3), 256, 0, stream>>>(q1w, xfftT, y1,
      nullptr, nullptr, 192, 192, 32768, 32768, 0, 0, 1);
  k_gemmT<64, 128, 4, 8><<<dim3(256, 3), 256, 0, stream>>>(q2w, y1, y2,
      nullptr, nullptr, 192, 192, 32768, 32768, 0, 0, 0);
  k_ifft<<<512, 256, 0, stream>>>(y2, xifft2);
  k_dwconv<<<dim3(32, 576), 256, 0, stream>>>(t, xifft2, qkvdww, qkvdwb, qkvp);
  k_attn<<<dim3(512, 6), 256, 0, stream>>>(qkvp, rpb, aoTok);
  k_gemmT<128, 64, 8, 4><<<dim3(3, 256), 256, 0, stream>>>(aoTok, projw, projo,
      projb, nullptr, 192, 192, 192, 192, 1, 2, 0);
  k_resid<<<8192, 256, 0, stream>>>(x, projo, xres, stats);
  k_lnT<<<dim3(1024, 6), 256, 0, stream>>>(xres, stats, ln2w, ln2b, yT);

  // --- FFN phase: per (batch, half-image strip); pout via split-K x3 ---
  for (int bb = 0; bb < 2; ++bb) {
    for (int ci = 0; ci < 2; ++ci) {
      int r0   = ci * 64;
      int row0 = (ci == 0) ? 0 : 60;
      k_gemmT<128, 128, 8, 8><<<dim3(68, 12), 256, 0, stream>>>(pinw,
          yT + bb * 16384 + row0 * WWW, ff0, nullptr, nullptr,
          192, 192, 32768, 8704, 0, 0, 0);
      k_ffmid<<<dim3(32, 768), 256, 0, stream>>>(ff0, dw3w, dw5w, dw31w, dw51w,
          x1cat, r0, row0);
      // pout split-K: 3 chunks of K=512 -> 576 blocks (vs 192 before)
      k_gemmSK<64, 128, 4, 8><<<dim3(64, 3, 3), 256, 0, stream>>>(poutw, x1cat,
          psum, 512, 1536, 8192, 192, 8192);
      size_t off = (size_t)bb * 3145728 + (size_t)r0 * WWW;
      k_red3<<<1536, 256, 0, stream>>>(psum, xres + off, out + off, 8192, 16384);
    }
  }
}